// Round 18
// baseline (244.026 us; speedup 1.0000x reference)
//
#include <hip/hip_runtime.h>
#include <hip/hip_fp16.h>

#define N_NODES 50000
#define N_EDGES 800000
#define HID 128
#define OUT_CH 64
#define NBUCK 196     // dst buckets of 256 nodes
#define HB 128        // blocks in bucket histogram (chunk = 6250 edges)
#define EPT 8         // edges per thread in bucket_scatter

typedef __attribute__((ext_vector_type(8))) _Float16 half8;
typedef __attribute__((ext_vector_type(4))) float floatx4;

// ---------------- fused prep: dst-bucket histogram + fp16 weight transpose ----------------

__global__ __launch_bounds__(256)
void prep_fused(const int* __restrict__ ei, int* __restrict__ bhist,
                const float* __restrict__ W1, const float* __restrict__ W2,
                const float* __restrict__ W3, const float* __restrict__ Wo,
                _Float16* __restrict__ wt1, _Float16* __restrict__ wt2,
                _Float16* __restrict__ wt3, _Float16* __restrict__ wto) {
    const int tid = threadIdx.x;
    if (blockIdx.x < HB) {
        __shared__ int h[NBUCK];
        for (int i = tid; i < NBUCK; i += 256) h[i] = 0;
        __syncthreads();
        const int chunk = (N_EDGES + HB - 1) / HB;
        const int e0 = blockIdx.x * chunk;
        const int e1 = min(e0 + chunk, N_EDGES);
        for (int e = e0 + tid; e < e1; e += 256)
            atomicAdd(&h[ei[N_EDGES + e] >> 8], 1);
        __syncthreads();
        for (int i = tid; i < NBUCK; i += 256) bhist[blockIdx.x * NBUCK + i] = h[i];
    } else {
        const int SZ = HID * HID;  // 16384
        int i = (blockIdx.x - HB) * 256 + tid;
        if (i < SZ) {
            int k = i >> 7, c = i & 127;
            wt1[(size_t)c * HID + k] = (_Float16)W1[i];
        } else if (i < 2 * SZ) {
            int j = i - SZ, k = j >> 7, c = j & 127;
            wt2[(size_t)c * HID + k] = (_Float16)W2[j];
        } else if (i < 3 * SZ) {
            int j = i - 2 * SZ, k = j >> 7, c = j & 127;
            wt3[(size_t)c * HID + k] = (_Float16)W3[j];
        } else if (i < 3 * SZ + HID * OUT_CH) {
            int j = i - 3 * SZ, k = j >> 6, c = j & 63;
            wto[(size_t)c * HID + k] = (_Float16)Wo[j];
        }
    }
}

__global__ __launch_bounds__(256)
void bucket_scan(const int* __restrict__ bhist, int* __restrict__ bucket_off,
                 int* __restrict__ bucket_cur, float* __restrict__ sum,
                 int* __restrict__ ticket) {
    __shared__ int s[256];
    const int tid = threadIdx.x;
    if (tid < OUT_CH) sum[tid] = 0.0f;
    if (tid == 0) *ticket = 0;
    int v = 0;
    if (tid < NBUCK)
        for (int b = 0; b < HB; b++) v += bhist[b * NBUCK + tid];
    s[tid] = v;
    __syncthreads();
    for (int off = 1; off < 256; off <<= 1) {
        int t = (tid >= off) ? s[tid - off] : 0;
        __syncthreads();
        s[tid] += t;
        __syncthreads();
    }
    if (tid < NBUCK) {
        int excl = s[tid] - v;
        bucket_off[tid] = excl;
        bucket_cur[tid] = excl;
    }
    if (tid == 0) bucket_off[NBUCK] = N_EDGES;
}

// scatter edges into 256-node dst buckets; per-(block,bucket) runs reserved with
// one global atomic each. Records split: esa = src (4B), dlo = dst&255 (1B).
__global__ __launch_bounds__(256)
void bucket_scatter(const int* __restrict__ ei, int* __restrict__ bucket_cur,
                    int* __restrict__ esa, unsigned char* __restrict__ dlo) {
    __shared__ int hist[NBUCK];
    __shared__ int grun[NBUCK];
    const int tid = threadIdx.x;
    for (int i = tid; i < NBUCK; i += 256) hist[i] = 0;
    __syncthreads();
    const int e0 = blockIdx.x * (256 * EPT);
    int src[EPT], dst[EPT], rank[EPT], bk[EPT];
#pragma unroll
    for (int j = 0; j < EPT; j++) {
        int e = e0 + j * 256 + tid;
        if (e < N_EDGES) {
            src[j] = ei[e];
            dst[j] = ei[N_EDGES + e];
            bk[j] = dst[j] >> 8;
            rank[j] = atomicAdd(&hist[bk[j]], 1);
        } else {
            bk[j] = -1;
        }
    }
    __syncthreads();
    for (int i = tid; i < NBUCK; i += 256)
        grun[i] = hist[i] ? atomicAdd(&bucket_cur[i], hist[i]) : 0;
    __syncthreads();
#pragma unroll
    for (int j = 0; j < EPT; j++)
        if (bk[j] >= 0) {
            int p = grun[bk[j]] + rank[j];
            esa[p] = src[j];
            dlo[p] = (unsigned char)(dst[j] & 255);
        }
}

// one 512-thread block per bucket (256 nodes): count, scan, emit row_start+dinv,
// place sources into final CSR order.
__global__ __launch_bounds__(512)
void node_sort(const int* __restrict__ esa, const unsigned char* __restrict__ dlo,
               const int* __restrict__ bucket_off, int* __restrict__ row_start,
               float* __restrict__ dinv, int* __restrict__ esrc) {
    __shared__ int cnt[256];
    __shared__ int s[256];
    __shared__ int cur[256];
    const int tid = threadIdx.x;
    const int b = blockIdx.x;
    if (tid < 256) cnt[tid] = 0;
    __syncthreads();
    const int off = bucket_off[b];
    const int end = bucket_off[b + 1];
    for (int i = off + tid; i < end; i += 512)
        atomicAdd(&cnt[dlo[i]], 1);
    __syncthreads();
    int v = 0;
    if (tid < 256) {
        v = cnt[tid];
        s[tid] = v;
    }
    __syncthreads();
    for (int o = 1; o < 256; o <<= 1) {
        int t = 0;
        if (tid < 256 && tid >= o) t = s[tid - o];
        __syncthreads();
        if (tid < 256) s[tid] += t;
        __syncthreads();
    }
    if (tid < 256) {
        const int gpos = off + s[tid] - v;   // this node's start in final CSR
        cur[tid] = gpos;
        const int node = b * 256 + tid;
        if (node < N_NODES) {
            row_start[node] = gpos;
            dinv[node] = rsqrtf(1.0f + (float)v);
        }
        if (b == NBUCK - 1 && tid == 0) row_start[N_NODES] = N_EDGES;
    }
    __syncthreads();
    for (int i = off + tid; i < end; i += 512) {
        int p = atomicAdd(&cur[dlo[i]], 1);
        esrc[p] = esa[i];
    }
}

// ---------------- MFMA GEMM: Y[n][OUT] = A[n][128] @ W, Wt is [OUT][128] ----------------
// Wave = 16 rows x OUT cols (OUT/16 16x16 tiles, K=128 -> 4 MFMA each). One block
// covers ALL columns (no y-dim) so A fragments are read once. No LDS staging.
// CONV_A: A is f32, converted in the fragment load. MEAN: fused column-sum
// reduction + last-block writes graph_preds via device-scope ticket.

template <int OUT, bool ADD_BIAS, bool SCALE, bool HALF_OUT, bool CONV_A, bool MEAN>
__global__ __launch_bounds__(256)
void gemm_mfma(const void* __restrict__ Av, const _Float16* __restrict__ Wt,
               const float* __restrict__ bias, const float* __restrict__ dinv,
               void* __restrict__ Yv, float* __restrict__ gsum,
               int* __restrict__ ticket, int n) {
    constexpr int NT = OUT / 16;               // col tiles per wave (8 or 4)
    const int tid  = threadIdx.x;
    const int lane = tid & 63;
    const int wv   = tid >> 6;
    const int m0   = blockIdx.x * 64 + wv * 16;
    const bool act = (m0 < n);
    if (!MEAN && !act) return;
    const int l15  = lane & 15;
    const int kb   = lane >> 4;                // 0..3

    half8 a[4];
    if (act) {
        if constexpr (CONV_A) {
            const float* arow = (const float*)Av + (size_t)(m0 + l15) * 128 + kb * 8;
#pragma unroll
            for (int j = 0; j < 4; j++) {
                float4 v0 = *(const float4*)(arow + j * 32);
                float4 v1 = *(const float4*)(arow + j * 32 + 4);
                union { __half2 h2[4]; half8 h8; } u;
                u.h2[0] = __floats2half2_rn(v0.x, v0.y);
                u.h2[1] = __floats2half2_rn(v0.z, v0.w);
                u.h2[2] = __floats2half2_rn(v1.x, v1.y);
                u.h2[3] = __floats2half2_rn(v1.z, v1.w);
                a[j] = u.h8;
            }
        } else {
            const _Float16* arow = (const _Float16*)Av + (size_t)(m0 + l15) * 128 + kb * 8;
#pragma unroll
            for (int j = 0; j < 4; j++) a[j] = *(const half8*)(arow + j * 32);
        }
    }

    const int rbase = m0 + kb * 4;             // rows this lane's D covers
    float4 dv = make_float4(1.f, 1.f, 1.f, 1.f);
    if constexpr (SCALE) {
        if (act) dv = *(const float4*)(dinv + rbase);
    }
    const float ds[4] = {dv.x, dv.y, dv.z, dv.w};

    float psum[NT];
    __shared__ float mred[4][OUT];

#pragma unroll
    for (int nt = 0; nt < NT; nt++) {
        const int col = nt * 16 + l15;
        floatx4 acc = {0.f, 0.f, 0.f, 0.f};
        if (act) {
            const _Float16* brow = Wt + (size_t)col * 128 + kb * 8;
#pragma unroll
            for (int j = 0; j < 4; j++) {
                half8 b = *(const half8*)(brow + j * 32);
                acc = __builtin_amdgcn_mfma_f32_16x16x32_f16(a[j], b, acc, 0, 0, 0);
            }
            if constexpr (HALF_OUT) {
                _Float16* Y = (_Float16*)Yv;
#pragma unroll
                for (int r = 0; r < 4; r++)
                    Y[(size_t)(rbase + r) * OUT + col] = (_Float16)(acc[r] * ds[r]);
            } else {
                float* Y = (float*)Yv;
                float bc = ADD_BIAS ? bias[col] : 0.f;
#pragma unroll
                for (int r = 0; r < 4; r++)
                    Y[(size_t)(rbase + r) * OUT + col] = acc[r] + bc;
            }
        }
        if constexpr (MEAN) psum[nt] = acc[0] + acc[1] + acc[2] + acc[3];
    }

    if constexpr (MEAN) {
#pragma unroll
        for (int nt = 0; nt < NT; nt++) {
            float p = psum[nt];
            p += __shfl_down(p, 32);
            p += __shfl_down(p, 16);
            if (lane < 16) mred[wv][nt * 16 + lane] = p;
        }
        __syncthreads();
        if (tid < OUT) {
            float s = mred[0][tid] + mred[1][tid] + mred[2][tid] + mred[3][tid];
            atomicAdd(&gsum[tid], s);
        }
        // last block finalizes graph_preds (device-scope ticket)
        __shared__ int winner;
        __syncthreads();
        if (tid == 0) {
            __threadfence();
            winner = (atomicAdd(ticket, 1) == (int)gridDim.x - 1) ? 1 : 0;
        }
        __syncthreads();
        if (winner && tid < OUT) {
            float v = atomicAdd(&gsum[tid], 0.0f);   // coherent read
            ((float*)Yv)[(size_t)N_NODES * OUT + tid] = v * (1.0f / N_NODES) + bias[tid];
        }
    }
}

// ---------------- fused aggregation: 16 lanes/node, 16B int4 gathers ----------------
// t is dinv-pre-scaled fp16. out[c] = relu(dinv[c]*(t[c] + sum_src t[src]) + b), fp16.

__global__ __launch_bounds__(256)
void aggregate_w(const _Float16* __restrict__ t, const int* __restrict__ row_start,
                 const int* __restrict__ esrc, const float* __restrict__ dinv,
                 const float* __restrict__ bias, _Float16* __restrict__ out) {
    const int tid = threadIdx.x;
    const int node = blockIdx.x * 16 + (tid >> 4);
    const int fo = tid & 15;   // int4 index: features 8*fo .. 8*fo+7
    if (node >= N_NODES) return;

    const int4* t4 = (const int4*)t;

    int4 sg = t4[(size_t)node * 16 + fo];       // self term (pre-scaled)
    float acc[8];
    {
        const __half2* h = (const __half2*)&sg;
#pragma unroll
        for (int q = 0; q < 4; q++) {
            float2 f = __half22float2(h[q]);
            acc[2 * q] = f.x;
            acc[2 * q + 1] = f.y;
        }
    }

    int k = row_start[node];
    const int k1 = row_start[node + 1];
    for (; k + 8 <= k1; k += 8) {
        int src[8];
#pragma unroll
        for (int u = 0; u < 8; u++) src[u] = esrc[k + u];
        int4 g[8];
#pragma unroll
        for (int u = 0; u < 8; u++) g[u] = t4[(size_t)src[u] * 16 + fo];
#pragma unroll
        for (int u = 0; u < 8; u++) {
            const __half2* h = (const __half2*)&g[u];
#pragma unroll
            for (int q = 0; q < 4; q++) {
                float2 f = __half22float2(h[q]);
                acc[2 * q] += f.x;
                acc[2 * q + 1] += f.y;
            }
        }
    }
    if (k + 4 <= k1) {
        int src[4];
#pragma unroll
        for (int u = 0; u < 4; u++) src[u] = esrc[k + u];
        int4 g[4];
#pragma unroll
        for (int u = 0; u < 4; u++) g[u] = t4[(size_t)src[u] * 16 + fo];
#pragma unroll
        for (int u = 0; u < 4; u++) {
            const __half2* h = (const __half2*)&g[u];
#pragma unroll
            for (int q = 0; q < 4; q++) {
                float2 f = __half22float2(h[q]);
                acc[2 * q] += f.x;
                acc[2 * q + 1] += f.y;
            }
        }
        k += 4;
    }
    for (; k < k1; k++) {
        int4 g = t4[(size_t)esrc[k] * 16 + fo];
        const __half2* h = (const __half2*)&g;
#pragma unroll
        for (int q = 0; q < 4; q++) {
            float2 f = __half22float2(h[q]);
            acc[2 * q] += f.x;
            acc[2 * q + 1] += f.y;
        }
    }

    const float d = dinv[node];
    const float4* b4 = (const float4*)bias;
    float4 b0 = b4[fo * 2], b1 = b4[fo * 2 + 1];
    const float bb[8] = {b0.x, b0.y, b0.z, b0.w, b1.x, b1.y, b1.z, b1.w};
    union { __half2 h2[4]; int4 i4; } u;
#pragma unroll
    for (int q = 0; q < 4; q++) {
        float lo = fmaxf(acc[2 * q] * d + bb[2 * q], 0.f);
        float hi = fmaxf(acc[2 * q + 1] * d + bb[2 * q + 1], 0.f);
        u.h2[q] = __floats2half2_rn(lo, hi);
    }
    ((int4*)out)[(size_t)node * 16 + fo] = u.i4;
}

// ---------------- launch ----------------

extern "C" void kernel_launch(void* const* d_in, const int* in_sizes, int n_in,
                              void* d_out, int out_size, void* d_ws, size_t ws_size,
                              hipStream_t stream) {
    const float* x  = (const float*)d_in[0];
    const int* ei   = (const int*)d_in[1];   // int32 on device
    const float* W1 = (const float*)d_in[2];
    const float* b1 = (const float*)d_in[3];
    const float* W2 = (const float*)d_in[4];
    const float* b2 = (const float*)d_in[5];
    const float* W3 = (const float*)d_in[6];
    const float* b3 = (const float*)d_in[7];
    const float* Wo = (const float*)d_in[8];
    const float* bo = (const float*)d_in[9];
    float* out = (float*)d_out;

    char* ws = (char*)d_ws;
    auto take = [&](size_t bytes) {
        char* p = ws;
        ws += (bytes + 255) & ~size_t(255);
        return (void*)p;
    };
    int*           bhist      = (int*)take((size_t)HB * NBUCK * 4);
    int*           bucket_off = (int*)take((size_t)(NBUCK + 1) * 4);
    int*           bucket_cur = (int*)take((size_t)NBUCK * 4);
    int*           esa        = (int*)take((size_t)N_EDGES * 4);
    unsigned char* dlo        = (unsigned char*)take((size_t)N_EDGES);
    int*           row_start  = (int*)take((size_t)(N_NODES + 1) * 4);
    float*         dinv       = (float*)take((size_t)N_NODES * 4);
    int*           esrc       = (int*)take((size_t)N_EDGES * 4);
    float*         sum        = (float*)take(OUT_CH * 4);
    int*           ticket     = (int*)take(256);
    _Float16*      wt1        = (_Float16*)take((size_t)HID * HID * 2);
    _Float16*      wt2        = (_Float16*)take((size_t)HID * HID * 2);
    _Float16*      wt3        = (_Float16*)take((size_t)HID * HID * 2);
    _Float16*      wto        = (_Float16*)take((size_t)HID * OUT_CH * 2);
    _Float16*      hA         = (_Float16*)take((size_t)N_NODES * HID * 2);
    _Float16*      hB         = (_Float16*)take((size_t)N_NODES * HID * 2);

    const int BS = 256;
    const int gScat = (N_EDGES + BS * EPT - 1) / (BS * EPT);
    const int gGemm = (N_NODES + 63) / 64;
    const int gAgg  = (N_NODES + 15) / 16;
    const int gWt   = (3 * HID * HID + HID * OUT_CH + BS - 1) / BS;

    // CSR build (bucketed, write-coalesced) + weight prep fused
    prep_fused<<<HB + gWt, BS, 0, stream>>>(ei, bhist, W1, W2, W3, Wo,
                                            wt1, wt2, wt3, wto);
    bucket_scan<<<1, BS, 0, stream>>>(bhist, bucket_off, bucket_cur, sum, ticket);
    bucket_scatter<<<gScat, BS, 0, stream>>>(ei, bucket_cur, esa, dlo);
    node_sort<<<NBUCK, 512, 0, stream>>>(esa, dlo, bucket_off, row_start, dinv, esrc);

    const float* bs[3] = {b1, b2, b3};

    // layer 1: f32 x converted in-kernel
    gemm_mfma<HID, false, true, true, true, false><<<gGemm, BS, 0, stream>>>(
        x, wt1, nullptr, dinv, hA, nullptr, nullptr, N_NODES);
    aggregate_w<<<gAgg, BS, 0, stream>>>(hA, row_start, esrc, dinv, bs[0], hB);

    // layers 2,3: fp16 chain
    const _Float16* wts[2] = {wt2, wt3};
    for (int layer = 0; layer < 2; layer++) {
        gemm_mfma<HID, false, true, true, false, false><<<gGemm, BS, 0, stream>>>(
            hB, wts[layer], nullptr, dinv, hA, nullptr, nullptr, N_NODES);
        aggregate_w<<<gAgg, BS, 0, stream>>>(hA, row_start, esrc, dinv,
                                             bs[layer + 1], hB);
    }

    // output projection + fused mean (ticketed finalize, no extra launch)
    gemm_mfma<OUT_CH, true, false, false, false, true><<<gGemm, BS, 0, stream>>>(
        hB, wto, bo, nullptr, out, sum, ticket, N_NODES);
}

// Round 19
// 236.698 us; speedup vs baseline: 1.0310x; 1.0310x over previous
//
#include <hip/hip_runtime.h>
#include <hip/hip_fp16.h>

#define N_NODES 50000
#define N_EDGES 800000
#define HID 128
#define OUT_CH 64
#define NBUCK 196     // dst buckets of 256 nodes
#define HB 128        // blocks in bucket histogram (chunk = 6250 edges)
#define EPT 8         // edges per thread in bucket_scatter

typedef __attribute__((ext_vector_type(8))) _Float16 half8;
typedef __attribute__((ext_vector_type(4))) float floatx4;

// ---------------- fused prep: dst-bucket histogram + fp16 weight transpose ----------------

__global__ __launch_bounds__(256)
void prep_fused(const int* __restrict__ ei, int* __restrict__ bhist,
                const float* __restrict__ W1, const float* __restrict__ W2,
                const float* __restrict__ W3, const float* __restrict__ Wo,
                _Float16* __restrict__ wt1, _Float16* __restrict__ wt2,
                _Float16* __restrict__ wt3, _Float16* __restrict__ wto) {
    const int tid = threadIdx.x;
    if (blockIdx.x < HB) {
        __shared__ int h[NBUCK];
        for (int i = tid; i < NBUCK; i += 256) h[i] = 0;
        __syncthreads();
        const int chunk = (N_EDGES + HB - 1) / HB;
        const int e0 = blockIdx.x * chunk;
        const int e1 = min(e0 + chunk, N_EDGES);
        for (int e = e0 + tid; e < e1; e += 256)
            atomicAdd(&h[ei[N_EDGES + e] >> 8], 1);
        __syncthreads();
        for (int i = tid; i < NBUCK; i += 256) bhist[blockIdx.x * NBUCK + i] = h[i];
    } else {
        const int SZ = HID * HID;  // 16384
        int i = (blockIdx.x - HB) * 256 + tid;
        if (i < SZ) {
            int k = i >> 7, c = i & 127;
            wt1[(size_t)c * HID + k] = (_Float16)W1[i];
        } else if (i < 2 * SZ) {
            int j = i - SZ, k = j >> 7, c = j & 127;
            wt2[(size_t)c * HID + k] = (_Float16)W2[j];
        } else if (i < 3 * SZ) {
            int j = i - 2 * SZ, k = j >> 7, c = j & 127;
            wt3[(size_t)c * HID + k] = (_Float16)W3[j];
        } else if (i < 3 * SZ + HID * OUT_CH) {
            int j = i - 3 * SZ, k = j >> 6, c = j & 63;
            wto[(size_t)c * HID + k] = (_Float16)Wo[j];
        }
    }
}

__global__ __launch_bounds__(256)
void bucket_scan(const int* __restrict__ bhist, int* __restrict__ bucket_off,
                 int* __restrict__ bucket_cur, float* __restrict__ sum,
                 int* __restrict__ ticket) {
    __shared__ int s[256];
    const int tid = threadIdx.x;
    if (tid < OUT_CH) sum[tid] = 0.0f;
    if (tid == 0) *ticket = 0;
    int v = 0;
    if (tid < NBUCK)
        for (int b = 0; b < HB; b++) v += bhist[b * NBUCK + tid];
    s[tid] = v;
    __syncthreads();
    for (int off = 1; off < 256; off <<= 1) {
        int t = (tid >= off) ? s[tid - off] : 0;
        __syncthreads();
        s[tid] += t;
        __syncthreads();
    }
    if (tid < NBUCK) {
        int excl = s[tid] - v;
        bucket_off[tid] = excl;
        bucket_cur[tid] = excl;
    }
    if (tid == 0) bucket_off[NBUCK] = N_EDGES;
}

// scatter edges into 256-node dst buckets; per-(block,bucket) runs reserved with
// one global atomic each. Records split: esa = src (4B), dlo = dst&255 (1B).
__global__ __launch_bounds__(256)
void bucket_scatter(const int* __restrict__ ei, int* __restrict__ bucket_cur,
                    int* __restrict__ esa, unsigned char* __restrict__ dlo) {
    __shared__ int hist[NBUCK];
    __shared__ int grun[NBUCK];
    const int tid = threadIdx.x;
    for (int i = tid; i < NBUCK; i += 256) hist[i] = 0;
    __syncthreads();
    const int e0 = blockIdx.x * (256 * EPT);
    int src[EPT], dst[EPT], rank[EPT], bk[EPT];
#pragma unroll
    for (int j = 0; j < EPT; j++) {
        int e = e0 + j * 256 + tid;
        if (e < N_EDGES) {
            src[j] = ei[e];
            dst[j] = ei[N_EDGES + e];
            bk[j] = dst[j] >> 8;
            rank[j] = atomicAdd(&hist[bk[j]], 1);
        } else {
            bk[j] = -1;
        }
    }
    __syncthreads();
    for (int i = tid; i < NBUCK; i += 256)
        grun[i] = hist[i] ? atomicAdd(&bucket_cur[i], hist[i]) : 0;
    __syncthreads();
#pragma unroll
    for (int j = 0; j < EPT; j++)
        if (bk[j] >= 0) {
            int p = grun[bk[j]] + rank[j];
            esa[p] = src[j];
            dlo[p] = (unsigned char)(dst[j] & 255);
        }
}

// one 512-thread block per bucket (256 nodes): count, scan, emit row_start+dinv,
// place sources into final CSR order.
__global__ __launch_bounds__(512)
void node_sort(const int* __restrict__ esa, const unsigned char* __restrict__ dlo,
               const int* __restrict__ bucket_off, int* __restrict__ row_start,
               float* __restrict__ dinv, int* __restrict__ esrc) {
    __shared__ int cnt[256];
    __shared__ int s[256];
    __shared__ int cur[256];
    const int tid = threadIdx.x;
    const int b = blockIdx.x;
    if (tid < 256) cnt[tid] = 0;
    __syncthreads();
    const int off = bucket_off[b];
    const int end = bucket_off[b + 1];
    for (int i = off + tid; i < end; i += 512)
        atomicAdd(&cnt[dlo[i]], 1);
    __syncthreads();
    int v = 0;
    if (tid < 256) {
        v = cnt[tid];
        s[tid] = v;
    }
    __syncthreads();
    for (int o = 1; o < 256; o <<= 1) {
        int t = 0;
        if (tid < 256 && tid >= o) t = s[tid - o];
        __syncthreads();
        if (tid < 256) s[tid] += t;
        __syncthreads();
    }
    if (tid < 256) {
        const int gpos = off + s[tid] - v;   // this node's start in final CSR
        cur[tid] = gpos;
        const int node = b * 256 + tid;
        if (node < N_NODES) {
            row_start[node] = gpos;
            dinv[node] = rsqrtf(1.0f + (float)v);
        }
        if (b == NBUCK - 1 && tid == 0) row_start[N_NODES] = N_EDGES;
    }
    __syncthreads();
    for (int i = off + tid; i < end; i += 512) {
        int p = atomicAdd(&cur[dlo[i]], 1);
        esrc[p] = esa[i];
    }
}

// ---------------- MFMA GEMM: Y[n][OUT] = A[n][128] @ W, Wt is [OUT][128] ----------------
// Wave = 16 rows x 64 cols (4 16x16 tiles, K=128 -> 4 MFMA each). No LDS staging.
// CONV_A: A is f32, converted in the fragment load. MEAN: fused column-sum
// reduction; last block (device-scope ticket) writes graph_preds directly.

template <int OUT, bool ADD_BIAS, bool SCALE, bool HALF_OUT, bool CONV_A, bool MEAN>
__global__ __launch_bounds__(256)
void gemm_mfma(const void* __restrict__ Av, const _Float16* __restrict__ Wt,
               const float* __restrict__ bias, const float* __restrict__ dinv,
               void* __restrict__ Yv, float* __restrict__ gsum,
               int* __restrict__ ticket, int n) {
    const int tid  = threadIdx.x;
    const int lane = tid & 63;
    const int wv   = tid >> 6;
    const int m0   = blockIdx.x * 64 + wv * 16;
    const bool act = (m0 < n);                 // n % 16 == 0: no partial bands
    if (!MEAN && !act) return;
    const int l15  = lane & 15;
    const int kb   = lane >> 4;                // 0..3
    const int col0 = blockIdx.y * 64;

    half8 a[4];
    if (act) {
        if constexpr (CONV_A) {
            const float* arow = (const float*)Av + (size_t)(m0 + l15) * 128 + kb * 8;
#pragma unroll
            for (int j = 0; j < 4; j++) {
                float4 v0 = *(const float4*)(arow + j * 32);
                float4 v1 = *(const float4*)(arow + j * 32 + 4);
                union { __half2 h2[4]; half8 h8; } u;
                u.h2[0] = __floats2half2_rn(v0.x, v0.y);
                u.h2[1] = __floats2half2_rn(v0.z, v0.w);
                u.h2[2] = __floats2half2_rn(v1.x, v1.y);
                u.h2[3] = __floats2half2_rn(v1.z, v1.w);
                a[j] = u.h8;
            }
        } else {
            const _Float16* arow = (const _Float16*)Av + (size_t)(m0 + l15) * 128 + kb * 8;
#pragma unroll
            for (int j = 0; j < 4; j++) a[j] = *(const half8*)(arow + j * 32);
        }
    }

    const int rbase = m0 + kb * 4;             // rows this lane's D covers
    float4 dv = make_float4(1.f, 1.f, 1.f, 1.f);
    if constexpr (SCALE) {
        if (act) dv = *(const float4*)(dinv + rbase);
    }
    const float ds[4] = {dv.x, dv.y, dv.z, dv.w};

    float psum[4];
    __shared__ float mred[4][64];

#pragma unroll
    for (int nt = 0; nt < 4; nt++) {
        const int col = col0 + nt * 16 + l15;
        floatx4 acc = {0.f, 0.f, 0.f, 0.f};
        if (act) {
            const _Float16* brow = Wt + (size_t)col * 128 + kb * 8;
#pragma unroll
            for (int j = 0; j < 4; j++) {
                half8 b = *(const half8*)(brow + j * 32);
                acc = __builtin_amdgcn_mfma_f32_16x16x32_f16(a[j], b, acc, 0, 0, 0);
            }
            if constexpr (HALF_OUT) {
                _Float16* Y = (_Float16*)Yv;
#pragma unroll
                for (int r = 0; r < 4; r++)
                    Y[(size_t)(rbase + r) * OUT + col] = (_Float16)(acc[r] * ds[r]);
            } else {
                float* Y = (float*)Yv;
                float bc = ADD_BIAS ? bias[col] : 0.f;
#pragma unroll
                for (int r = 0; r < 4; r++)
                    Y[(size_t)(rbase + r) * OUT + col] = acc[r] + bc;
            }
        }
        if constexpr (MEAN) psum[nt] = acc[0] + acc[1] + acc[2] + acc[3];
    }

    if constexpr (MEAN) {
#pragma unroll
        for (int nt = 0; nt < 4; nt++) {
            float p = psum[nt];
            p += __shfl_down(p, 32);
            p += __shfl_down(p, 16);
            if (lane < 16) mred[wv][nt * 16 + lane] = p;
        }
        __syncthreads();
        if (tid < 64) {
            float s = mred[0][tid] + mred[1][tid] + mred[2][tid] + mred[3][tid];
            atomicAdd(&gsum[tid], s);
        }
        // last block finalizes graph_preds (device-scope ticket, saves a launch)
        __shared__ int winner;
        __syncthreads();
        if (tid == 0) {
            __threadfence();
            winner = (atomicAdd(ticket, 1) ==
                      (int)(gridDim.x * gridDim.y) - 1) ? 1 : 0;
        }
        __syncthreads();
        if (winner && tid < 64) {
            float v = atomicAdd(&gsum[tid], 0.0f);   // coherent read
            ((float*)Yv)[(size_t)N_NODES * OUT_CH + tid] =
                v * (1.0f / N_NODES) + bias[tid];
        }
    }
}

// ---------------- fused aggregation: 16 lanes/node, 16B int4 gathers ----------------
// t is dinv-pre-scaled fp16. out[c] = relu(dinv[c]*(t[c] + sum_src t[src]) + b), fp16.

__global__ __launch_bounds__(256)
void aggregate_w(const _Float16* __restrict__ t, const int* __restrict__ row_start,
                 const int* __restrict__ esrc, const float* __restrict__ dinv,
                 const float* __restrict__ bias, _Float16* __restrict__ out) {
    const int tid = threadIdx.x;
    const int node = blockIdx.x * 16 + (tid >> 4);
    const int fo = tid & 15;   // int4 index: features 8*fo .. 8*fo+7
    if (node >= N_NODES) return;

    const int4* t4 = (const int4*)t;

    int4 sg = t4[(size_t)node * 16 + fo];       // self term (pre-scaled)
    float acc[8];
    {
        const __half2* h = (const __half2*)&sg;
#pragma unroll
        for (int q = 0; q < 4; q++) {
            float2 f = __half22float2(h[q]);
            acc[2 * q] = f.x;
            acc[2 * q + 1] = f.y;
        }
    }

    int k = row_start[node];
    const int k1 = row_start[node + 1];
    for (; k + 8 <= k1; k += 8) {
        int src[8];
#pragma unroll
        for (int u = 0; u < 8; u++) src[u] = esrc[k + u];
        int4 g[8];
#pragma unroll
        for (int u = 0; u < 8; u++) g[u] = t4[(size_t)src[u] * 16 + fo];
#pragma unroll
        for (int u = 0; u < 8; u++) {
            const __half2* h = (const __half2*)&g[u];
#pragma unroll
            for (int q = 0; q < 4; q++) {
                float2 f = __half22float2(h[q]);
                acc[2 * q] += f.x;
                acc[2 * q + 1] += f.y;
            }
        }
    }
    if (k + 4 <= k1) {
        int src[4];
#pragma unroll
        for (int u = 0; u < 4; u++) src[u] = esrc[k + u];
        int4 g[4];
#pragma unroll
        for (int u = 0; u < 4; u++) g[u] = t4[(size_t)src[u] * 16 + fo];
#pragma unroll
        for (int u = 0; u < 4; u++) {
            const __half2* h = (const __half2*)&g[u];
#pragma unroll
            for (int q = 0; q < 4; q++) {
                float2 f = __half22float2(h[q]);
                acc[2 * q] += f.x;
                acc[2 * q + 1] += f.y;
            }
        }
        k += 4;
    }
    for (; k < k1; k++) {
        int4 g = t4[(size_t)esrc[k] * 16 + fo];
        const __half2* h = (const __half2*)&g;
#pragma unroll
        for (int q = 0; q < 4; q++) {
            float2 f = __half22float2(h[q]);
            acc[2 * q] += f.x;
            acc[2 * q + 1] += f.y;
        }
    }

    const float d = dinv[node];
    const float4* b4 = (const float4*)bias;
    float4 b0 = b4[fo * 2], b1 = b4[fo * 2 + 1];
    const float bb[8] = {b0.x, b0.y, b0.z, b0.w, b1.x, b1.y, b1.z, b1.w};
    union { __half2 h2[4]; int4 i4; } u;
#pragma unroll
    for (int q = 0; q < 4; q++) {
        float lo = fmaxf(acc[2 * q] * d + bb[2 * q], 0.f);
        float hi = fmaxf(acc[2 * q + 1] * d + bb[2 * q + 1], 0.f);
        u.h2[q] = __floats2half2_rn(lo, hi);
    }
    ((int4*)out)[(size_t)node * 16 + fo] = u.i4;
}

// ---------------- launch ----------------

extern "C" void kernel_launch(void* const* d_in, const int* in_sizes, int n_in,
                              void* d_out, int out_size, void* d_ws, size_t ws_size,
                              hipStream_t stream) {
    const float* x  = (const float*)d_in[0];
    const int* ei   = (const int*)d_in[1];   // int32 on device
    const float* W1 = (const float*)d_in[2];
    const float* b1 = (const float*)d_in[3];
    const float* W2 = (const float*)d_in[4];
    const float* b2 = (const float*)d_in[5];
    const float* W3 = (const float*)d_in[6];
    const float* b3 = (const float*)d_in[7];
    const float* Wo = (const float*)d_in[8];
    const float* bo = (const float*)d_in[9];
    float* out = (float*)d_out;

    char* ws = (char*)d_ws;
    auto take = [&](size_t bytes) {
        char* p = ws;
        ws += (bytes + 255) & ~size_t(255);
        return (void*)p;
    };
    int*           bhist      = (int*)take((size_t)HB * NBUCK * 4);
    int*           bucket_off = (int*)take((size_t)(NBUCK + 1) * 4);
    int*           bucket_cur = (int*)take((size_t)NBUCK * 4);
    int*           esa        = (int*)take((size_t)N_EDGES * 4);
    unsigned char* dlo        = (unsigned char*)take((size_t)N_EDGES);
    int*           row_start  = (int*)take((size_t)(N_NODES + 1) * 4);
    float*         dinv       = (float*)take((size_t)N_NODES * 4);
    int*           esrc       = (int*)take((size_t)N_EDGES * 4);
    float*         sum        = (float*)take(OUT_CH * 4);
    int*           ticket     = (int*)take(256);
    _Float16*      wt1        = (_Float16*)take((size_t)HID * HID * 2);
    _Float16*      wt2        = (_Float16*)take((size_t)HID * HID * 2);
    _Float16*      wt3        = (_Float16*)take((size_t)HID * HID * 2);
    _Float16*      wto        = (_Float16*)take((size_t)HID * OUT_CH * 2);
    _Float16*      hA         = (_Float16*)take((size_t)N_NODES * HID * 2);
    _Float16*      hB         = (_Float16*)take((size_t)N_NODES * HID * 2);

    const int BS = 256;
    const int gScat = (N_EDGES + BS * EPT - 1) / (BS * EPT);
    const int gGemm = (N_NODES + 63) / 64;
    const int gAgg  = (N_NODES + 15) / 16;
    const int gWt   = (3 * HID * HID + HID * OUT_CH + BS - 1) / BS;

    // CSR build (bucketed, write-coalesced) + weight prep fused
    prep_fused<<<HB + gWt, BS, 0, stream>>>(ei, bhist, W1, W2, W3, Wo,
                                            wt1, wt2, wt3, wto);
    bucket_scan<<<1, BS, 0, stream>>>(bhist, bucket_off, bucket_cur, sum, ticket);
    bucket_scatter<<<gScat, BS, 0, stream>>>(ei, bucket_cur, esa, dlo);
    node_sort<<<NBUCK, 512, 0, stream>>>(esa, dlo, bucket_off, row_start, dinv, esrc);

    const float* bs[3] = {b1, b2, b3};

    // layer 1: f32 x converted in-kernel (y=2: occupancy > A-reread savings, r18 lesson)
    gemm_mfma<HID, false, true, true, true, false><<<dim3(gGemm, 2), BS, 0, stream>>>(
        x, wt1, nullptr, dinv, hA, nullptr, nullptr, N_NODES);
    aggregate_w<<<gAgg, BS, 0, stream>>>(hA, row_start, esrc, dinv, bs[0], hB);

    // layers 2,3: fp16 chain
    const _Float16* wts[2] = {wt2, wt3};
    for (int layer = 0; layer < 2; layer++) {
        gemm_mfma<HID, false, true, true, false, false><<<dim3(gGemm, 2), BS, 0, stream>>>(
            hB, wts[layer], nullptr, dinv, hA, nullptr, nullptr, N_NODES);
        aggregate_w<<<gAgg, BS, 0, stream>>>(hA, row_start, esrc, dinv,
                                             bs[layer + 1], hB);
    }

    // output projection + fused mean (ticketed finalize, no extra launch)
    gemm_mfma<OUT_CH, true, false, false, false, true><<<dim3(gGemm, 1), BS, 0, stream>>>(
        hB, wto, bo, nullptr, out, sum, ticket, N_NODES);
}

// Round 20
// 232.249 us; speedup vs baseline: 1.0507x; 1.0192x over previous
//
#include <hip/hip_runtime.h>
#include <hip/hip_fp16.h>

#define N_NODES 50000
#define N_EDGES 800000
#define HID 128
#define OUT_CH 64
#define NBUCK 196     // dst buckets of 256 nodes
#define HB 128        // blocks in bucket histogram (chunk = 6250 edges)
#define EPT 8         // edges per thread in bucket_scatter

typedef __attribute__((ext_vector_type(8))) _Float16 half8;
typedef __attribute__((ext_vector_type(4))) float floatx4;

// ---------------- fused prep: dst-bucket histogram + fp16 weight transpose ----------------

__global__ __launch_bounds__(256)
void prep_fused(const int* __restrict__ ei, int* __restrict__ bhist,
                const float* __restrict__ W1, const float* __restrict__ W2,
                const float* __restrict__ W3, const float* __restrict__ Wo,
                _Float16* __restrict__ wt1, _Float16* __restrict__ wt2,
                _Float16* __restrict__ wt3, _Float16* __restrict__ wto) {
    const int tid = threadIdx.x;
    if (blockIdx.x < HB) {
        __shared__ int h[NBUCK];
        for (int i = tid; i < NBUCK; i += 256) h[i] = 0;
        __syncthreads();
        const int chunk = (N_EDGES + HB - 1) / HB;
        const int e0 = blockIdx.x * chunk;
        const int e1 = min(e0 + chunk, N_EDGES);
        for (int e = e0 + tid; e < e1; e += 256)
            atomicAdd(&h[ei[N_EDGES + e] >> 8], 1);
        __syncthreads();
        for (int i = tid; i < NBUCK; i += 256) bhist[blockIdx.x * NBUCK + i] = h[i];
    } else {
        const int SZ = HID * HID;  // 16384
        int i = (blockIdx.x - HB) * 256 + tid;
        if (i < SZ) {
            int k = i >> 7, c = i & 127;
            wt1[(size_t)c * HID + k] = (_Float16)W1[i];
        } else if (i < 2 * SZ) {
            int j = i - SZ, k = j >> 7, c = j & 127;
            wt2[(size_t)c * HID + k] = (_Float16)W2[j];
        } else if (i < 3 * SZ) {
            int j = i - 2 * SZ, k = j >> 7, c = j & 127;
            wt3[(size_t)c * HID + k] = (_Float16)W3[j];
        } else if (i < 3 * SZ + HID * OUT_CH) {
            int j = i - 3 * SZ, k = j >> 6, c = j & 63;
            wto[(size_t)c * HID + k] = (_Float16)Wo[j];
        }
    }
}

__global__ __launch_bounds__(256)
void bucket_scan(const int* __restrict__ bhist, int* __restrict__ bucket_off,
                 int* __restrict__ bucket_cur, float* __restrict__ sum) {
    __shared__ int s[256];
    const int tid = threadIdx.x;
    if (tid < OUT_CH) sum[tid] = 0.0f;
    int v = 0;
    if (tid < NBUCK)
        for (int b = 0; b < HB; b++) v += bhist[b * NBUCK + tid];
    s[tid] = v;
    __syncthreads();
    for (int off = 1; off < 256; off <<= 1) {
        int t = (tid >= off) ? s[tid - off] : 0;
        __syncthreads();
        s[tid] += t;
        __syncthreads();
    }
    if (tid < NBUCK) {
        int excl = s[tid] - v;
        bucket_off[tid] = excl;
        bucket_cur[tid] = excl;
    }
    if (tid == 0) bucket_off[NBUCK] = N_EDGES;
}

// scatter edges into 256-node dst buckets; per-(block,bucket) runs reserved with
// one global atomic each. Records split: esa = src (4B), dlo = dst&255 (1B).
__global__ __launch_bounds__(256)
void bucket_scatter(const int* __restrict__ ei, int* __restrict__ bucket_cur,
                    int* __restrict__ esa, unsigned char* __restrict__ dlo) {
    __shared__ int hist[NBUCK];
    __shared__ int grun[NBUCK];
    const int tid = threadIdx.x;
    for (int i = tid; i < NBUCK; i += 256) hist[i] = 0;
    __syncthreads();
    const int e0 = blockIdx.x * (256 * EPT);
    int src[EPT], dst[EPT], rank[EPT], bk[EPT];
#pragma unroll
    for (int j = 0; j < EPT; j++) {
        int e = e0 + j * 256 + tid;
        if (e < N_EDGES) {
            src[j] = ei[e];
            dst[j] = ei[N_EDGES + e];
            bk[j] = dst[j] >> 8;
            rank[j] = atomicAdd(&hist[bk[j]], 1);
        } else {
            bk[j] = -1;
        }
    }
    __syncthreads();
    for (int i = tid; i < NBUCK; i += 256)
        grun[i] = hist[i] ? atomicAdd(&bucket_cur[i], hist[i]) : 0;
    __syncthreads();
#pragma unroll
    for (int j = 0; j < EPT; j++)
        if (bk[j] >= 0) {
            int p = grun[bk[j]] + rank[j];
            esa[p] = src[j];
            dlo[p] = (unsigned char)(dst[j] & 255);
        }
}

// one 512-thread block per bucket (256 nodes): count, scan, emit row_start+dinv,
// place sources into final CSR order.
__global__ __launch_bounds__(512)
void node_sort(const int* __restrict__ esa, const unsigned char* __restrict__ dlo,
               const int* __restrict__ bucket_off, int* __restrict__ row_start,
               float* __restrict__ dinv, int* __restrict__ esrc) {
    __shared__ int cnt[256];
    __shared__ int s[256];
    __shared__ int cur[256];
    const int tid = threadIdx.x;
    const int b = blockIdx.x;
    if (tid < 256) cnt[tid] = 0;
    __syncthreads();
    const int off = bucket_off[b];
    const int end = bucket_off[b + 1];
    for (int i = off + tid; i < end; i += 512)
        atomicAdd(&cnt[dlo[i]], 1);
    __syncthreads();
    int v = 0;
    if (tid < 256) {
        v = cnt[tid];
        s[tid] = v;
    }
    __syncthreads();
    for (int o = 1; o < 256; o <<= 1) {
        int t = 0;
        if (tid < 256 && tid >= o) t = s[tid - o];
        __syncthreads();
        if (tid < 256) s[tid] += t;
        __syncthreads();
    }
    if (tid < 256) {
        const int gpos = off + s[tid] - v;   // this node's start in final CSR
        cur[tid] = gpos;
        const int node = b * 256 + tid;
        if (node < N_NODES) {
            row_start[node] = gpos;
            dinv[node] = rsqrtf(1.0f + (float)v);
        }
        if (b == NBUCK - 1 && tid == 0) row_start[N_NODES] = N_EDGES;
    }
    __syncthreads();
    for (int i = off + tid; i < end; i += 512) {
        int p = atomicAdd(&cur[dlo[i]], 1);
        esrc[p] = esa[i];
    }
}

// ---------------- MFMA GEMM: Y[n][OUT] = A[n][128] @ W, Wt is [OUT][128] ----------------
// Wave = 16 rows x 64 cols (4 16x16 tiles, K=128 -> 4 MFMA each). No LDS staging.
// CONV_A: A is f32, converted in the fragment load. MEAN: fused column-sum
// reduction into gsum (one atomicAdd per col per block).

template <int OUT, bool ADD_BIAS, bool SCALE, bool HALF_OUT, bool CONV_A, bool MEAN>
__global__ __launch_bounds__(256)
void gemm_mfma(const void* __restrict__ Av, const _Float16* __restrict__ Wt,
               const float* __restrict__ bias, const float* __restrict__ dinv,
               void* __restrict__ Yv, float* __restrict__ gsum, int n) {
    const int tid  = threadIdx.x;
    const int lane = tid & 63;
    const int wv   = tid >> 6;
    const int m0   = blockIdx.x * 64 + wv * 16;
    const bool act = (m0 < n);                 // n % 16 == 0: no partial bands
    if (!MEAN && !act) return;
    const int l15  = lane & 15;
    const int kb   = lane >> 4;                // 0..3
    const int col0 = blockIdx.y * 64;

    half8 a[4];
    if (act) {
        if constexpr (CONV_A) {
            const float* arow = (const float*)Av + (size_t)(m0 + l15) * 128 + kb * 8;
#pragma unroll
            for (int j = 0; j < 4; j++) {
                float4 v0 = *(const float4*)(arow + j * 32);
                float4 v1 = *(const float4*)(arow + j * 32 + 4);
                union { __half2 h2[4]; half8 h8; } u;
                u.h2[0] = __floats2half2_rn(v0.x, v0.y);
                u.h2[1] = __floats2half2_rn(v0.z, v0.w);
                u.h2[2] = __floats2half2_rn(v1.x, v1.y);
                u.h2[3] = __floats2half2_rn(v1.z, v1.w);
                a[j] = u.h8;
            }
        } else {
            const _Float16* arow = (const _Float16*)Av + (size_t)(m0 + l15) * 128 + kb * 8;
#pragma unroll
            for (int j = 0; j < 4; j++) a[j] = *(const half8*)(arow + j * 32);
        }
    }

    const int rbase = m0 + kb * 4;             // rows this lane's D covers
    float4 dv = make_float4(1.f, 1.f, 1.f, 1.f);
    if constexpr (SCALE) {
        if (act) dv = *(const float4*)(dinv + rbase);
    }
    const float ds[4] = {dv.x, dv.y, dv.z, dv.w};

    float psum[4];
    __shared__ float mred[4][64];

#pragma unroll
    for (int nt = 0; nt < 4; nt++) {
        const int col = col0 + nt * 16 + l15;
        floatx4 acc = {0.f, 0.f, 0.f, 0.f};
        if (act) {
            const _Float16* brow = Wt + (size_t)col * 128 + kb * 8;
#pragma unroll
            for (int j = 0; j < 4; j++) {
                half8 b = *(const half8*)(brow + j * 32);
                acc = __builtin_amdgcn_mfma_f32_16x16x32_f16(a[j], b, acc, 0, 0, 0);
            }
            if constexpr (HALF_OUT) {
                _Float16* Y = (_Float16*)Yv;
#pragma unroll
                for (int r = 0; r < 4; r++)
                    Y[(size_t)(rbase + r) * OUT + col] = (_Float16)(acc[r] * ds[r]);
            } else {
                float* Y = (float*)Yv;
                float bc = ADD_BIAS ? bias[col] : 0.f;
#pragma unroll
                for (int r = 0; r < 4; r++)
                    Y[(size_t)(rbase + r) * OUT + col] = acc[r] + bc;
            }
        }
        if constexpr (MEAN) psum[nt] = acc[0] + acc[1] + acc[2] + acc[3];
    }

    if constexpr (MEAN) {
#pragma unroll
        for (int nt = 0; nt < 4; nt++) {
            float p = psum[nt];
            p += __shfl_down(p, 32);
            p += __shfl_down(p, 16);
            if (lane < 16) mred[wv][nt * 16 + lane] = p;
        }
        __syncthreads();
        if (tid < 64) {
            float s = mred[0][tid] + mred[1][tid] + mred[2][tid] + mred[3][tid];
            atomicAdd(&gsum[tid], s);
        }
    }
}

// ---------------- fused aggregation: 16 lanes/node, 16B int4 gathers ----------------
// t is dinv-pre-scaled fp16. out[c] = relu(dinv[c]*(t[c] + sum_src t[src]) + b), fp16.

__global__ __launch_bounds__(256)
void aggregate_w(const _Float16* __restrict__ t, const int* __restrict__ row_start,
                 const int* __restrict__ esrc, const float* __restrict__ dinv,
                 const float* __restrict__ bias, _Float16* __restrict__ out) {
    const int tid = threadIdx.x;
    const int node = blockIdx.x * 16 + (tid >> 4);
    const int fo = tid & 15;   // int4 index: features 8*fo .. 8*fo+7
    if (node >= N_NODES) return;

    const int4* t4 = (const int4*)t;

    int4 sg = t4[(size_t)node * 16 + fo];       // self term (pre-scaled)
    float acc[8];
    {
        const __half2* h = (const __half2*)&sg;
#pragma unroll
        for (int q = 0; q < 4; q++) {
            float2 f = __half22float2(h[q]);
            acc[2 * q] = f.x;
            acc[2 * q + 1] = f.y;
        }
    }

    int k = row_start[node];
    const int k1 = row_start[node + 1];
    for (; k + 8 <= k1; k += 8) {
        int src[8];
#pragma unroll
        for (int u = 0; u < 8; u++) src[u] = esrc[k + u];
        int4 g[8];
#pragma unroll
        for (int u = 0; u < 8; u++) g[u] = t4[(size_t)src[u] * 16 + fo];
#pragma unroll
        for (int u = 0; u < 8; u++) {
            const __half2* h = (const __half2*)&g[u];
#pragma unroll
            for (int q = 0; q < 4; q++) {
                float2 f = __half22float2(h[q]);
                acc[2 * q] += f.x;
                acc[2 * q + 1] += f.y;
            }
        }
    }
    if (k + 4 <= k1) {
        int src[4];
#pragma unroll
        for (int u = 0; u < 4; u++) src[u] = esrc[k + u];
        int4 g[4];
#pragma unroll
        for (int u = 0; u < 4; u++) g[u] = t4[(size_t)src[u] * 16 + fo];
#pragma unroll
        for (int u = 0; u < 4; u++) {
            const __half2* h = (const __half2*)&g[u];
#pragma unroll
            for (int q = 0; q < 4; q++) {
                float2 f = __half22float2(h[q]);
                acc[2 * q] += f.x;
                acc[2 * q + 1] += f.y;
            }
        }
        k += 4;
    }
    for (; k < k1; k++) {
        int4 g = t4[(size_t)esrc[k] * 16 + fo];
        const __half2* h = (const __half2*)&g;
#pragma unroll
        for (int q = 0; q < 4; q++) {
            float2 f = __half22float2(h[q]);
            acc[2 * q] += f.x;
            acc[2 * q + 1] += f.y;
        }
    }

    const float d = dinv[node];
    const float4* b4 = (const float4*)bias;
    float4 b0 = b4[fo * 2], b1 = b4[fo * 2 + 1];
    const float bb[8] = {b0.x, b0.y, b0.z, b0.w, b1.x, b1.y, b1.z, b1.w};
    union { __half2 h2[4]; int4 i4; } u;
#pragma unroll
    for (int q = 0; q < 4; q++) {
        float lo = fmaxf(acc[2 * q] * d + bb[2 * q], 0.f);
        float hi = fmaxf(acc[2 * q + 1] * d + bb[2 * q + 1], 0.f);
        u.h2[q] = __floats2half2_rn(lo, hi);
    }
    ((int4*)out)[(size_t)node * 16 + fo] = u.i4;
}

// ---------------- mean finalize (bias folded in here; gsum is pre-bias) ----------------

__global__ void mean_final(const float* __restrict__ sum, const float* __restrict__ bias,
                           float* __restrict__ out) {
    int j = threadIdx.x;
    if (j < OUT_CH) out[N_NODES * OUT_CH + j] = sum[j] * (1.0f / N_NODES) + bias[j];
}

// ---------------- launch ----------------

extern "C" void kernel_launch(void* const* d_in, const int* in_sizes, int n_in,
                              void* d_out, int out_size, void* d_ws, size_t ws_size,
                              hipStream_t stream) {
    const float* x  = (const float*)d_in[0];
    const int* ei   = (const int*)d_in[1];   // int32 on device
    const float* W1 = (const float*)d_in[2];
    const float* b1 = (const float*)d_in[3];
    const float* W2 = (const float*)d_in[4];
    const float* b2 = (const float*)d_in[5];
    const float* W3 = (const float*)d_in[6];
    const float* b3 = (const float*)d_in[7];
    const float* Wo = (const float*)d_in[8];
    const float* bo = (const float*)d_in[9];
    float* out = (float*)d_out;

    char* ws = (char*)d_ws;
    auto take = [&](size_t bytes) {
        char* p = ws;
        ws += (bytes + 255) & ~size_t(255);
        return (void*)p;
    };
    int*           bhist      = (int*)take((size_t)HB * NBUCK * 4);
    int*           bucket_off = (int*)take((size_t)(NBUCK + 1) * 4);
    int*           bucket_cur = (int*)take((size_t)NBUCK * 4);
    int*           esa        = (int*)take((size_t)N_EDGES * 4);
    unsigned char* dlo        = (unsigned char*)take((size_t)N_EDGES);
    int*           row_start  = (int*)take((size_t)(N_NODES + 1) * 4);
    float*         dinv       = (float*)take((size_t)N_NODES * 4);
    int*           esrc       = (int*)take((size_t)N_EDGES * 4);
    float*         sum        = (float*)take(OUT_CH * 4);
    _Float16*      wt1        = (_Float16*)take((size_t)HID * HID * 2);
    _Float16*      wt2        = (_Float16*)take((size_t)HID * HID * 2);
    _Float16*      wt3        = (_Float16*)take((size_t)HID * HID * 2);
    _Float16*      wto        = (_Float16*)take((size_t)HID * OUT_CH * 2);
    _Float16*      hA         = (_Float16*)take((size_t)N_NODES * HID * 2);
    _Float16*      hB         = (_Float16*)take((size_t)N_NODES * HID * 2);

    const int BS = 256;
    const int gScat = (N_EDGES + BS * EPT - 1) / (BS * EPT);
    const int gGemm = (N_NODES + 63) / 64;
    const int gAgg  = (N_NODES + 15) / 16;
    const int gWt   = (3 * HID * HID + HID * OUT_CH + BS - 1) / BS;

    // CSR build (bucketed, write-coalesced) + weight prep fused
    prep_fused<<<HB + gWt, BS, 0, stream>>>(ei, bhist, W1, W2, W3, Wo,
                                            wt1, wt2, wt3, wto);
    bucket_scan<<<1, BS, 0, stream>>>(bhist, bucket_off, bucket_cur, sum);
    bucket_scatter<<<gScat, BS, 0, stream>>>(ei, bucket_cur, esa, dlo);
    node_sort<<<NBUCK, 512, 0, stream>>>(esa, dlo, bucket_off, row_start, dinv, esrc);

    const float* bs[3] = {b1, b2, b3};

    // layer 1: f32 x converted in-kernel (y=2: occupancy > A-reread savings, r18 lesson)
    gemm_mfma<HID, false, true, true, true, false><<<dim3(gGemm, 2), BS, 0, stream>>>(
        x, wt1, nullptr, dinv, hA, nullptr, N_NODES);
    aggregate_w<<<gAgg, BS, 0, stream>>>(hA, row_start, esrc, dinv, bs[0], hB);

    // layers 2,3: fp16 chain
    const _Float16* wts[2] = {wt2, wt3};
    for (int layer = 0; layer < 2; layer++) {
        gemm_mfma<HID, false, true, true, false, false><<<dim3(gGemm, 2), BS, 0, stream>>>(
            hB, wts[layer], nullptr, dinv, hA, nullptr, N_NODES);
        aggregate_w<<<gAgg, BS, 0, stream>>>(hA, row_start, esrc, dinv,
                                             bs[layer + 1], hB);
    }

    // output projection + fused mean partial sums
    gemm_mfma<OUT_CH, true, false, false, false, true><<<dim3(gGemm, 1), BS, 0, stream>>>(
        hB, wto, bo, nullptr, out, sum, N_NODES);
    mean_final<<<1, 64, 0, stream>>>(sum, bo, out);
}